// Round 8
// baseline (256.488 us; speedup 1.0000x reference)
//
#include <hip/hip_runtime.h>

#define NB   8192
#define HD   1024
#define HFD  1152
#define NK0  64
#define NK1  256
#define DD   128

typedef __attribute__((ext_vector_type(4))) float  f32x4;
typedef __attribute__((ext_vector_type(8))) __bf16 bf16x8;

__device__ __forceinline__ unsigned short f2bf(float f) {
  unsigned int u = __float_as_uint(f);
  u += 0x7fffu + ((u >> 16) & 1u);
  return (unsigned short)(u >> 16);
}
__device__ __forceinline__ unsigned int pack2(float a, float b) {
  return (unsigned int)f2bf(a) | ((unsigned int)f2bf(b) << 16);
}
__device__ __forceinline__ uint4 pack8(const float4 a, const float4 b) {
  return make_uint4(pack2(a.x, a.y), pack2(a.z, a.w), pack2(b.x, b.y), pack2(b.z, b.w));
}
__device__ __forceinline__ void gload_lds16(const void* g, void* l) {
  __builtin_amdgcn_global_load_lds(
      (const __attribute__((address_space(1))) void*)g,
      (__attribute__((address_space(3))) void*)l, 16, 0, 0);
}

// device-scope ticket barrier: all 256 blocks co-resident (cooperative launch)
#define GRID_BARRIER(PH)                                                        \
  {                                                                             \
    __syncthreads();                                                            \
    __threadfence();                                                            \
    if (t == 0) {                                                               \
      __hip_atomic_fetch_add(bar, 1u, __ATOMIC_ACQ_REL, __HIP_MEMORY_SCOPE_AGENT); \
      while (__hip_atomic_load(bar, __ATOMIC_ACQUIRE, __HIP_MEMORY_SCOPE_AGENT) \
             < 256u * (PH)) {}                                                  \
    }                                                                           \
    __syncthreads();                                                            \
  }

__global__ __launch_bounds__(512) void k_all(
    const float* __restrict__ x, const float* __restrict__ Wc,
    const float* __restrict__ Wf, const float* __restrict__ fcb,
    const float* __restrict__ ccb, const float* __restrict__ bc,
    const float* __restrict__ gc, const float* __restrict__ betac,
    const float* __restrict__ bfv, const float* __restrict__ gf,
    const float* __restrict__ betaf,
    unsigned short* __restrict__ Wcomb, unsigned short* __restrict__ Wfz,
    unsigned short* __restrict__ fcbbf, unsigned short* __restrict__ ccbbf,
    float* __restrict__ cn_all, float* __restrict__ cn_c,
    float* __restrict__ out0, float* __restrict__ out1,
    float* __restrict__ outL,
    unsigned short* __restrict__ zf_bf, float* __restrict__ zfn,
    int* __restrict__ ci_g, float* __restrict__ coarse_partial,
    float* __restrict__ fine_partial, unsigned int* __restrict__ bar)
{
  extern __shared__ char smem[];
  const int t = threadIdx.x, bid = blockIdx.x;
  const int lane = t & 63, wid = t >> 6;
  const int l15 = lane & 15, lhi = lane >> 4;

  // ===== Phase 0: weight/codebook bf16 conversion + norms =====
  {
    const int gtid = bid * 512 + t;
    for (long i = gtid; i < 297984; i += 131072) {
      if (i < 16384) {                       // Wc -> Wcomb[0:128]
        long e = i * 8;
        const float4 a = *(const float4*)&Wc[e];
        const float4 b = *(const float4*)&Wc[e + 4];
        *(uint4*)&Wcomb[e] = pack8(a, b);
      } else if (i < 34816) {                // Wf -> Wcomb[128:256] + Wfz
        long e = (i - 16384) * 8;
        const float4 a = *(const float4*)&Wf[e];
        const float4 b = *(const float4*)&Wf[e + 4];
        const uint4 pk = pack8(a, b);
        const int row = (int)(e / HFD), c = (int)(e % HFD);
        if (c < 1024) *(uint4*)&Wcomb[(size_t)(128 + row) * HD + c] = pk;
        else          *(uint4*)&Wfz[(size_t)row * DD + (c - 1024)] = pk;
      } else if (i < 296960) {               // fcb -> fcbbf
        long e = (i - 34816) * 8;
        const float4 a = *(const float4*)&fcb[e];
        const float4 b = *(const float4*)&fcb[e + 4];
        *(uint4*)&fcbbf[e] = pack8(a, b);
      } else {                               // ccb -> ccbbf
        long e = (i - 296960) * 8;
        const float4 a = *(const float4*)&ccb[e];
        const float4 b = *(const float4*)&ccb[e + 4];
        *(uint4*)&ccbbf[e] = pack8(a, b);
      }
    }
    const int gtid2 = bid * 512 + t;
    if (gtid2 < 16448) {                     // fine + coarse codebook norms
      const float* r = (gtid2 < 16384) ? (fcb + (size_t)gtid2 * DD)
                                       : (ccb + (size_t)(gtid2 - 16384) * DD);
      float s = 0.f;
#pragma unroll
      for (int i = 0; i < 32; ++i) {
        const float4 v = *(const float4*)&r[i * 4];
        s += v.x * v.x + v.y * v.y + v.z * v.z + v.w * v.w;
      }
      if (gtid2 < 16384) cn_all[gtid2] = s;
      else               cn_c[gtid2 - 16384] = s;
    }
  }
  GRID_BARRIER(1)

  // ===== Phase 1: merged GEMM (N=256) + LN + coarse VQ + fused zf =====
  {
    const int m0 = bid * 32;
    f32x4 acc[2][2];
#pragma unroll
    for (int m = 0; m < 2; ++m)
#pragma unroll
      for (int n = 0; n < 2; ++n) acc[m][n] = (f32x4){0.f, 0.f, 0.f, 0.f};

    const int axr = t >> 4;
    const int axc = (t & 15) << 2;
    float4 ra[4];

#define LOADA(tile, slot) \
  ra[slot] = *(const float4*)&x[(size_t)(m0 + axr) * HD + (size_t)(tile) * 64 + axc];
#define WRITEA(bufoff, slot)                                                    \
  *(uint2*)(smem + (bufoff) + (axr << 7) + ((((t & 15) << 3)) ^ ((axr & 7) << 4))) = \
      make_uint2(pack2(ra[slot].x, ra[slot].y), pack2(ra[slot].z, ra[slot].w));
#define STAGEB(bufoff, kt)                                                      \
  {                                                                             \
    _Pragma("unroll")                                                           \
    for (int j = 0; j < 4; ++j) {                                               \
      const int br = (wid << 5) + (j << 3) + (lane >> 3);                       \
      const char* bsrc = (const char*)Wcomb +                                   \
          (((size_t)br * HD + (size_t)(kt) * 64) << 1) +                        \
          (((lane & 7) << 4) ^ ((br & 7) << 4));                                \
      gload_lds16(bsrc, smem + (bufoff) + 4096 + (((wid << 5) + (j << 3)) << 7)); \
    }                                                                           \
  }

    LOADA(0, 0); LOADA(1, 1); LOADA(2, 2); LOADA(3, 3);

    for (int kt = -2; kt < 16; ++kt) {
      const int st = kt + 2;
      const int stc = st > 15 ? 15 : st;
      const int sbuf = (st % 3) * 36864;
      const int slot = st & 3;
      WRITEA(sbuf, slot);
      STAGEB(sbuf, stc);
      {
        const int lt = (kt + 6 > 15) ? 15 : (kt + 6);
        LOADA(lt, slot);
      }
      if (kt >= 0) {
        asm volatile("s_waitcnt vmcnt(10) lgkmcnt(0)" ::: "memory");
        __builtin_amdgcn_s_barrier();
        __builtin_amdgcn_sched_barrier(0);
        const char* bufA = smem + (kt % 3) * 36864;
        const char* bufB = bufA + 4096;
#pragma unroll
        for (int ks = 0; ks < 2; ++ks) {
          const int kb = (ks << 6) + (lhi << 4);
          const int sa = kb ^ ((l15 & 7) << 4);
          bf16x8 a0 = *(const bf16x8*)(bufA + (l15 << 7) + sa);
          bf16x8 a1 = *(const bf16x8*)(bufA + ((l15 + 16) << 7) + sa);
#pragma unroll
          for (int n = 0; n < 2; ++n) {
            const int rb = (wid << 5) + (n << 4) + l15;
            bf16x8 b = *(const bf16x8*)(bufB + (rb << 7) + (kb ^ ((rb & 7) << 4)));
            acc[0][n] = __builtin_amdgcn_mfma_f32_16x16x32_bf16(a0, b, acc[0][n], 0, 0, 0);
            acc[1][n] = __builtin_amdgcn_mfma_f32_16x16x32_bf16(a1, b, acc[1][n], 0, 0, 0);
          }
        }
        asm volatile("" ::: "memory");
        __builtin_amdgcn_s_barrier();
      }
    }
#undef LOADA
#undef WRITEA
#undef STAGEB

    __syncthreads();

    int*   cxS = (int*)  smem;
    unsigned short* zqb = (unsigned short*)(smem + 128);
    float* zcf          = (float*)(smem + 9216);
    float* zff          = (float*)(smem + 26112);
    unsigned short* cbb = (unsigned short*)(smem + 43008);
    unsigned short* Wz  = (unsigned short*)(smem + 43008);
    unsigned short* zbb = (unsigned short*)(smem + 78336);
    float* zn  = (float*)(smem + 87040);
    float* cnS = (float*)(smem + 87168);
    float* dmS = (float*)(smem + 87424);
    int*   imS = (int*)  (smem + 87936);

    if (wid < 4) {
#pragma unroll
      for (int m = 0; m < 2; ++m)
#pragma unroll
        for (int n = 0; n < 2; ++n)
#pragma unroll
          for (int r = 0; r < 4; ++r) {
            int row = (m << 4) + (lhi << 2) + r;
            int col = (wid << 5) + (n << 4) + l15;
            zcf[row * 132 + col] = acc[m][n][r] + bc[col];
          }
    } else {
#pragma unroll
      for (int m = 0; m < 2; ++m)
#pragma unroll
        for (int n = 0; n < 2; ++n)
#pragma unroll
          for (int r = 0; r < 4; ++r) {
            int row = (m << 4) + (lhi << 2) + r;
            int col = ((wid - 4) << 5) + (n << 4) + l15;
            zff[row * 132 + col] = acc[m][n][r] + bfv[col];
          }
    }
#pragma unroll
    for (int i = 0; i < 2; ++i) {
      int idx = t + i * 512;
      int row = idx >> 4, c8 = (idx & 15) << 3;
      *(uint4*)&cbb[row * 136 + c8] = *(const uint4*)&ccbbf[(row << 7) + c8];
    }
    if (t < 64) cnS[t] = cn_c[t];
    __syncthreads();

    {  // LN(z_c)
      const int r = t >> 4, p = t & 15;
      float v[8];
      const float4 u0 = *(const float4*)&zcf[r * 132 + (p << 3)];
      const float4 u1 = *(const float4*)&zcf[r * 132 + (p << 3) + 4];
      v[0]=u0.x; v[1]=u0.y; v[2]=u0.z; v[3]=u0.w; v[4]=u1.x; v[5]=u1.y; v[6]=u1.z; v[7]=u1.w;
      float s = 0.f, s2 = 0.f;
#pragma unroll
      for (int j = 0; j < 8; ++j) { s += v[j]; s2 += v[j] * v[j]; }
#pragma unroll
      for (int off = 1; off < 16; off <<= 1) { s += __shfl_xor(s, off); s2 += __shfl_xor(s2, off); }
      const float mu   = s * (1.f / 128.f);
      const float rstd = rsqrtf(s2 * (1.f / 128.f) - mu * mu + 1e-5f);
      float s2n = 0.f;
#pragma unroll
      for (int j = 0; j < 8; ++j) {
        int col = (p << 3) + j;
        float vv = (v[j] - mu) * rstd * gc[col] + betac[col];
        v[j] = vv; s2n += vv * vv;
      }
#pragma unroll
      for (int off = 1; off < 16; off <<= 1) s2n += __shfl_xor(s2n, off);
      if (p == 0) zn[r] = s2n;
      *(uint4*)&zbb[r * 136 + (p << 3)] =
          make_uint4(pack2(v[0], v[1]), pack2(v[2], v[3]), pack2(v[4], v[5]), pack2(v[6], v[7]));
    }
    __syncthreads();

    {  // coarse distances via MFMA
      const int cg = wid & 3, zg = wid >> 2;
      f32x4 dacc = (f32x4){0.f, 0.f, 0.f, 0.f};
#pragma unroll
      for (int ks = 0; ks < 4; ++ks) {
        const int lk = (ks << 5) + (lhi << 3);
        bf16x8 a = *(const bf16x8*)&cbb[((cg << 4) + l15) * 136 + lk];
        bf16x8 b = *(const bf16x8*)&zbb[((zg << 4) + l15) * 136 + lk];
        dacc = __builtin_amdgcn_mfma_f32_16x16x32_bf16(a, b, dacc, 0, 0, 0);
      }
      float bd = 3.4e38f; int bi = 0;
#pragma unroll
      for (int r = 0; r < 4; ++r) {
        int code = (cg << 4) + (lhi << 2) + r;
        float d = cnS[code] - 2.f * dacc[r];
        if (d < bd || (d == bd && code < bi)) { bd = d; bi = code; }
      }
#pragma unroll
      for (int off = 16; off < 64; off <<= 1) {
        float od = __shfl_xor(bd, off); int oi = __shfl_xor(bi, off);
        if (od < bd || (od == bd && oi < bi)) { bd = od; bi = oi; }
      }
      if (lhi == 0) { dmS[cg * 32 + (zg << 4) + l15] = bd; imS[cg * 32 + (zg << 4) + l15] = bi; }
    }
    __syncthreads();

    if (t < 32) {
      float bd = dmS[t]; int bi = imS[t];
#pragma unroll
      for (int w = 1; w < 4; ++w) {
        float od = dmS[w * 32 + t]; int oi = imS[w * 32 + t];
        if (od < bd || (od == bd && oi < bi)) { bd = od; bi = oi; }
      }
      ci_g[m0 + t] = bi;
      cxS[t] = bi;
      float lp = bd + zn[t];
#pragma unroll
      for (int off = 1; off < 32; off <<= 1) lp += __shfl_xor(lp, off);
      if (t == 0) coarse_partial[bid] = lp;
    }
    __syncthreads();

    {  // stage Wfz + zcq(bf16); write out0
#pragma unroll
      for (int i = 0; i < 4; ++i) {
        int idx = t + i * 512;
        int row = idx >> 4, c8 = (idx & 15) << 3;
        *(uint4*)&Wz[row * 136 + c8] = *(const uint4*)&Wfz[(row << 7) + c8];
      }
      const int r = t >> 4, p = t & 15;
      const int c = cxS[r];
      *(uint4*)&zqb[r * 136 + (p << 3)] = *(const uint4*)&ccbbf[(c << 7) + (p << 3)];
      const float4 q0 = *(const float4*)&ccb[(c << 7) + (p << 3)];
      const float4 q1 = *(const float4*)&ccb[(c << 7) + (p << 3) + 4];
      *(float4*)&out0[(size_t)(m0 + r) * DD + (p << 3)]     = q0;
      *(float4*)&out0[(size_t)(m0 + r) * DD + (p << 3) + 4] = q1;
    }
    __syncthreads();

    {  // zff += zcq @ Wfz^T
      f32x4 a2[2];
      a2[0] = (f32x4){0.f, 0.f, 0.f, 0.f};
      a2[1] = (f32x4){0.f, 0.f, 0.f, 0.f};
#pragma unroll
      for (int ks = 0; ks < 4; ++ks) {
        const int lk = (ks << 5) + (lhi << 3);
        bf16x8 a0 = *(const bf16x8*)&zqb[l15 * 136 + lk];
        bf16x8 a1 = *(const bf16x8*)&zqb[(16 + l15) * 136 + lk];
        bf16x8 b  = *(const bf16x8*)&Wz[((wid << 4) + l15) * 136 + lk];
        a2[0] = __builtin_amdgcn_mfma_f32_16x16x32_bf16(a0, b, a2[0], 0, 0, 0);
        a2[1] = __builtin_amdgcn_mfma_f32_16x16x32_bf16(a1, b, a2[1], 0, 0, 0);
      }
#pragma unroll
      for (int m = 0; m < 2; ++m)
#pragma unroll
        for (int r = 0; r < 4; ++r)
          zff[((m << 4) + (lhi << 2) + r) * 132 + (wid << 4) + l15] += a2[m][r];
    }
    __syncthreads();

    {  // LN(z_f) -> zf_bf + zfn
      const int r = t >> 4, p = t & 15;
      float v[8];
      const float4 u0 = *(const float4*)&zff[r * 132 + (p << 3)];
      const float4 u1 = *(const float4*)&zff[r * 132 + (p << 3) + 4];
      v[0]=u0.x; v[1]=u0.y; v[2]=u0.z; v[3]=u0.w; v[4]=u1.x; v[5]=u1.y; v[6]=u1.z; v[7]=u1.w;
      float s = 0.f, s2 = 0.f;
#pragma unroll
      for (int j = 0; j < 8; ++j) { s += v[j]; s2 += v[j] * v[j]; }
#pragma unroll
      for (int off = 1; off < 16; off <<= 1) { s += __shfl_xor(s, off); s2 += __shfl_xor(s2, off); }
      const float mu   = s * (1.f / 128.f);
      const float rstd = rsqrtf(s2 * (1.f / 128.f) - mu * mu + 1e-5f);
      float s2n = 0.f;
      unsigned int o[4];
#pragma unroll
      for (int jj = 0; jj < 4; ++jj) {
        int col = (p << 3) + 2 * jj;
        float v0 = (v[2 * jj]     - mu) * rstd * gf[col]     + betaf[col];
        float v1 = (v[2 * jj + 1] - mu) * rstd * gf[col + 1] + betaf[col + 1];
        s2n += v0 * v0 + v1 * v1;
        o[jj] = pack2(v0, v1);
      }
#pragma unroll
      for (int off = 1; off < 16; off <<= 1) s2n += __shfl_xor(s2n, off);
      if (p == 0) zfn[m0 + r] = s2n;
      *(uint4*)&zf_bf[(size_t)(m0 + r) * DD + (p << 3)] = make_uint4(o[0], o[1], o[2], o[3]);
    }
  }
  GRID_BARRIER(2)

  // ===== Phase 2: fine VQ (block -> (g = bid>>2, cx = bid&3)) =====
  {
    unsigned short* Vb  = (unsigned short*)smem;            // [256][136]
    unsigned short* zfL = (unsigned short*)(smem + 69632);  // [32][136]
    int*   list = (int*)  (smem + 78336);                   // [2048]
    int*   ridS = (int*)  (smem + 86528);                   // [32]
    float* dmS  = (float*)(smem + 86656);                   // [8][32]
    int*   imS  = (int*)  (smem + 87680);                   // [8][32]
    int*   fiS  = (int*)  (smem + 88704);                   // [32]
    int*   wsum = (int*)  (smem + 88832);                   // [16]

    const int g = bid >> 2, cx = bid & 3;

    // stage group codebook first (latency hides under the scan)
#pragma unroll
    for (int i = 0; i < 8; ++i) {
      int idx = t + i * 512; int row = idx >> 4, c8 = (idx & 15) * 8;
      *(uint4*)&Vb[row * 136 + c8] = *(const uint4*)&fcbbf[((size_t)g * NK1 + row) * DD + c8];
    }
    float cnr[2];
#pragma unroll
    for (int n = 0; n < 2; ++n) cnr[n] = cn_all[g * NK1 + wid * 32 + n * 16 + l15];

    // deterministic compaction of {i : ci_g[i]==g}; 512 thr x 16 ints
    const int seg = t * 16;
    int mcount = 0;
#pragma unroll
    for (int q = 0; q < 16; ++q) mcount += (ci_g[seg + q] == g);
    int v = mcount;
#pragma unroll
    for (int off = 1; off < 64; off <<= 1) {
      int o = __shfl_up(v, off);
      if (lane >= off) v += o;
    }
    if (lane == 63) wsum[wid] = v;
    __syncthreads();
    if (t == 0) {
      int run = 0;
#pragma unroll
      for (int w = 0; w < 8; ++w) { int c = wsum[w]; wsum[w] = run; run += c; }
      wsum[8] = run;
    }
    __syncthreads();
    const int total = wsum[8];
    const int tcap = total > 2048 ? 2048 : total;
    {
      int j = wsum[wid] + v - mcount;
      for (int q = 0; q < 16; ++q) {
        if (ci_g[seg + q] == g) { if (j < 2048) list[j] = seg + q; ++j; }
      }
    }
    __syncthreads();

    float lp = 0.f;
    for (int r0 = cx * 32; r0 < tcap; r0 += 128) {
      __syncthreads();
      if (t < 32) ridS[t] = (r0 + t < tcap) ? list[r0 + t] : -1;
      __syncthreads();
      {
        int row = t >> 4, c8 = (t & 15) * 8;
        int rid = ridS[row];
        uint4 vv = make_uint4(0u, 0u, 0u, 0u);
        if (rid >= 0) vv = *(const uint4*)&zf_bf[(size_t)rid * DD + c8];
        *(uint4*)&zfL[row * 136 + c8] = vv;
      }
      __syncthreads();
      f32x4 acc2[2][2];
#pragma unroll
      for (int m = 0; m < 2; ++m)
#pragma unroll
        for (int n = 0; n < 2; ++n) acc2[m][n] = (f32x4){0.f, 0.f, 0.f, 0.f};
#pragma unroll
      for (int ks = 0; ks < 4; ++ks) {
        const int lk = ks * 32 + lhi * 8;
        bf16x8 a0 = *(const bf16x8*)&zfL[l15 * 136 + lk];
        bf16x8 a1 = *(const bf16x8*)&zfL[(16 + l15) * 136 + lk];
#pragma unroll
        for (int n = 0; n < 2; ++n) {
          bf16x8 b = *(const bf16x8*)&Vb[(wid * 32 + n * 16 + l15) * 136 + lk];
          acc2[0][n] = __builtin_amdgcn_mfma_f32_16x16x32_bf16(a0, b, acc2[0][n], 0, 0, 0);
          acc2[1][n] = __builtin_amdgcn_mfma_f32_16x16x32_bf16(a1, b, acc2[1][n], 0, 0, 0);
        }
      }
#pragma unroll
      for (int m = 0; m < 2; ++m)
#pragma unroll
        for (int r = 0; r < 4; ++r) {
          float bd = 3.4e38f; int bi = 0;
#pragma unroll
          for (int n = 0; n < 2; ++n) {
            int code = wid * 32 + n * 16 + l15;
            float d = cnr[n] - 2.f * acc2[m][n][r];
            if (d < bd || (d == bd && code < bi)) { bd = d; bi = code; }
          }
#pragma unroll
          for (int off = 1; off < 16; off <<= 1) {
            float od = __shfl_xor(bd, off); int oi = __shfl_xor(bi, off);
            if (od < bd || (od == bd && oi < bi)) { bd = od; bi = oi; }
          }
          if (l15 == 0) {
            int row = m * 16 + lhi * 4 + r;
            dmS[wid * 32 + row] = bd; imS[wid * 32 + row] = bi;
          }
        }
      __syncthreads();
      if (t < 32) {
        float bd = dmS[t]; int bi = imS[t];
#pragma unroll
        for (int w = 1; w < 8; ++w) {
          float od = dmS[w * 32 + t]; int oi = imS[w * 32 + t];
          if (od < bd || (od == bd && oi < bi)) { bd = od; bi = oi; }
        }
        fiS[t] = bi;
        int rid = ridS[t];
        if (rid >= 0) lp += bd + zfn[rid];
      }
      __syncthreads();
      {
        const int r = t >> 4, p = t & 15;
        const int rid = ridS[r];
        if (rid >= 0) {
          const float* qr = &fcb[((size_t)g * NK1 + fiS[r]) * DD + p * 8];
          float* orow = &out1[(size_t)rid * DD + p * 8];
          *(float4*)&orow[0] = *(const float4*)&qr[0];
          *(float4*)&orow[4] = *(const float4*)&qr[4];
        }
      }
    }
#pragma unroll
    for (int off = 1; off < 32; off <<= 1) lp += __shfl_xor(lp, off);
    if (t == 0) fine_partial[bid] = lp;
  }
  GRID_BARRIER(3)

  // ===== Phase 3: loss reduce (block 0, wave 0) =====
  if (bid == 0 && wid == 0) {
    float s = 0.f;
#pragma unroll
    for (int i = 0; i < 4; ++i)
      s += coarse_partial[lane + i * 64] + fine_partial[lane + i * 64];
#pragma unroll
    for (int off = 1; off < 64; off <<= 1) s += __shfl_xor(s, off);
    if (lane == 0) outL[0] = 1.25f * s / 1048576.0f;
  }
}

// ---- launcher -------------------------------------------------------------
extern "C" void kernel_launch(void* const* d_in, const int* in_sizes, int n_in,
                              void* d_out, int out_size, void* d_ws, size_t ws_size,
                              hipStream_t stream) {
  const float* x     = (const float*)d_in[0];
  const float* Wc    = (const float*)d_in[1];
  const float* bc    = (const float*)d_in[2];
  const float* gc    = (const float*)d_in[3];
  const float* betac = (const float*)d_in[4];
  const float* ccb   = (const float*)d_in[5];
  const float* Wf    = (const float*)d_in[6];
  const float* bfv   = (const float*)d_in[7];
  const float* gf    = (const float*)d_in[8];
  const float* betaf = (const float*)d_in[9];
  const float* fcb   = (const float*)d_in[10];

  float* out0 = (float*)d_out;
  float* out1 = out0 + (size_t)NB * DD;
  float* outL = out0 + (size_t)2 * NB * DD;

  char* ws = (char*)d_ws;
  unsigned short* Wcomb  = (unsigned short*)(ws);
  unsigned short* Wfz    = (unsigned short*)(ws + 524288);
  unsigned short* fcbbf  = (unsigned short*)(ws + 557056);
  unsigned short* ccbbf  = (unsigned short*)(ws + 4751360);
  float*          cn_all = (float*)(ws + 4767744);
  float*          cn_c   = (float*)(ws + 4833280);
  unsigned short* zf_bf  = (unsigned short*)(ws + 4833536);
  float*          zfn    = (float*)(ws + 6930688);
  int*            ci_g   = (int*)(ws + 6963456);
  float* coarse_partial  = (float*)(ws + 6996224);
  float* fine_partial    = (float*)(ws + 6998272);
  unsigned int*   bar    = (unsigned int*)(ws + 6999296);

  hipFuncSetAttribute(reinterpret_cast<const void*>(k_all),
                      hipFuncAttributeMaxDynamicSharedMemorySize, 110592);

  hipMemsetAsync((void*)bar, 0, 64, stream);

  void* args[] = {
    (void*)&x, (void*)&Wc, (void*)&Wf, (void*)&fcb, (void*)&ccb,
    (void*)&bc, (void*)&gc, (void*)&betac, (void*)&bfv, (void*)&gf, (void*)&betaf,
    (void*)&Wcomb, (void*)&Wfz, (void*)&fcbbf, (void*)&ccbbf,
    (void*)&cn_all, (void*)&cn_c,
    (void*)&out0, (void*)&out1, (void*)&outL,
    (void*)&zf_bf, (void*)&zfn, (void*)&ci_g,
    (void*)&coarse_partial, (void*)&fine_partial, (void*)&bar
  };
  hipLaunchCooperativeKernel(reinterpret_cast<const void*>(k_all),
                             dim3(256), dim3(512), args, 110592, stream);
}

// Round 9
// 73.330 us; speedup vs baseline: 3.4977x; 3.4977x over previous
//
#include <hip/hip_runtime.h>

#define NB   8192
#define HD   1024
#define HFD  1152
#define NK0  64
#define NK1  256
#define DD   128

typedef __attribute__((ext_vector_type(4))) float  f32x4;
typedef __attribute__((ext_vector_type(8))) __bf16 bf16x8;

__device__ __forceinline__ unsigned short f2bf(float f) {
  unsigned int u = __float_as_uint(f);
  u += 0x7fffu + ((u >> 16) & 1u);
  return (unsigned short)(u >> 16);
}
__device__ __forceinline__ unsigned int pack2(float a, float b) {
  return (unsigned int)f2bf(a) | ((unsigned int)f2bf(b) << 16);
}
__device__ __forceinline__ uint4 pack8(const float4 a, const float4 b) {
  return make_uint4(pack2(a.x, a.y), pack2(a.z, a.w), pack2(b.x, b.y), pack2(b.z, b.w));
}

// ---- KG2: everything except fine VQ. grid 256 x 512, 2 kernels total. -----
// B rows 0..127 = Wc, 128..255 = Wf[:, :1024]; f32 -> bf16 in-register.
// K-loop: reg-slot dbuf, raw s_barrier + lgkmcnt(0) only (no vmcnt drains).
__global__ __launch_bounds__(512) void kG2(
    const float* __restrict__ x, const float* __restrict__ Wc,
    const float* __restrict__ Wf, const float* __restrict__ ccb,
    const float* __restrict__ bc, const float* __restrict__ gc,
    const float* __restrict__ betac, const float* __restrict__ bfv,
    const float* __restrict__ gf, const float* __restrict__ betaf,
    float* __restrict__ out0, unsigned short* __restrict__ zf_bf,
    float* __restrict__ zfn, int* __restrict__ ci_g,
    float* __restrict__ coarse_partial, unsigned int* __restrict__ donecnt)
{
  extern __shared__ char smem[];
  const int t = threadIdx.x, bid = blockIdx.x;
  const int lane = t & 63, wid = t >> 6;
  const int l15 = lane & 15, lhi = lane >> 4;
  const int m0 = bid * 32;

  if (bid == 0 && t == 0)
    __hip_atomic_store(donecnt, 0u, __ATOMIC_RELAXED, __HIP_MEMORY_SCOPE_AGENT);

  f32x4 acc[2][2];
#pragma unroll
  for (int m = 0; m < 2; ++m)
#pragma unroll
    for (int n = 0; n < 2; ++n) acc[m][n] = (f32x4){0.f, 0.f, 0.f, 0.f};

  const int axr = t >> 4;          // A row 0..31
  const int axc = (t & 15) << 2;   // A f32 col
  float4 raA[2];
  float4 rbB[2][8];

#define LOADT(kt, s)                                                           \
  {                                                                            \
    raA[s] = *(const float4*)&x[(size_t)(m0 + axr) * HD + (size_t)(kt) * 64 + axc]; \
    _Pragma("unroll")                                                          \
    for (int j = 0; j < 4; ++j) {                                              \
      const int br = (wid << 5) + (j << 3) + (lane >> 3);                      \
      const float* bp = (br < 128 ? Wc + (size_t)br * HD                       \
                                  : Wf + (size_t)(br - 128) * HFD)             \
                        + (size_t)(kt) * 64 + ((lane & 7) << 3);               \
      rbB[s][2 * j]     = *(const float4*)bp;                                  \
      rbB[s][2 * j + 1] = *(const float4*)(bp + 4);                            \
    }                                                                          \
  }
#define WRITET(bufoff, s)                                                      \
  {                                                                            \
    *(uint2*)(smem + (bufoff) + (axr << 7) + ((((t & 15) << 3)) ^ ((axr & 7) << 4))) = \
        make_uint2(pack2(raA[s].x, raA[s].y), pack2(raA[s].z, raA[s].w));      \
    _Pragma("unroll")                                                          \
    for (int j = 0; j < 4; ++j) {                                              \
      const int br = (wid << 5) + (j << 3) + (lane >> 3);                      \
      *(uint4*)(smem + (bufoff) + 4096 + (br << 7) +                           \
                ((((lane & 7) << 4)) ^ ((br & 7) << 4))) =                     \
          pack8(rbB[s][2 * j], rbB[s][2 * j + 1]);                             \
    }                                                                          \
  }

  LOADT(0, 0);
  LOADT(1, 1);
#pragma unroll
  for (int kt = 0; kt < 16; ++kt) {
    const int s = kt & 1;
    const int bo = s * 36864;
    WRITET(bo, s);                       // compiler waits vmcnt for slot regs
    if (kt < 14) LOADT(kt + 2, s);       // refill slot (after consume, in order)
    asm volatile("s_waitcnt lgkmcnt(0)" ::: "memory");
    __builtin_amdgcn_s_barrier();
    __builtin_amdgcn_sched_barrier(0);
    const char* bufA = smem + bo;
    const char* bufB = bufA + 4096;
#pragma unroll
    for (int ks = 0; ks < 2; ++ks) {
      const int kb = (ks << 6) + (lhi << 4);
      const int sa = kb ^ ((l15 & 7) << 4);
      bf16x8 a0 = *(const bf16x8*)(bufA + (l15 << 7) + sa);
      bf16x8 a1 = *(const bf16x8*)(bufA + ((l15 + 16) << 7) + sa);
#pragma unroll
      for (int n = 0; n < 2; ++n) {
        const int rb = (wid << 5) + (n << 4) + l15;
        bf16x8 b = *(const bf16x8*)(bufB + (rb << 7) + (kb ^ ((rb & 7) << 4)));
        acc[0][n] = __builtin_amdgcn_mfma_f32_16x16x32_bf16(a0, b, acc[0][n], 0, 0, 0);
        acc[1][n] = __builtin_amdgcn_mfma_f32_16x16x32_bf16(a1, b, acc[1][n], 0, 0, 0);
      }
    }
    asm volatile("" ::: "memory");
    __builtin_amdgcn_s_barrier();
  }
#undef LOADT
#undef WRITET

  __syncthreads();

  // ---- epilogue LDS overlay ----
  int*   cxS = (int*)  smem;                              // [32]
  unsigned short* zqb = (unsigned short*)(smem + 128);    // [32][136]
  float* zcf          = (float*)(smem + 9216);            // [32][132] (E1-E2)
  float* zff          = (float*)(smem + 26112);           // [32][132] (E1-E7)
  unsigned short* cbb = (unsigned short*)(smem + 43008);  // [64][136] (E1-E3)
  unsigned short* Wz  = (unsigned short*)(smem + 43008);  // [128][136](E5-E6)
  unsigned short* zbb = (unsigned short*)(smem + 78336);  // [32][136] (E2-E3)
  float* zn  = (float*)(smem + 87040);                    // [32]
  float* cnS = (float*)(smem + 87168);                    // [64]
  float* dmS = (float*)(smem + 87424);                    // [4][32]
  int*   imS = (int*)  (smem + 87936);                    // [4][32]

  // E1: distribute acc; stage coarse codebook bf16 from f32 + norms (shfl, f32)
  if (wid < 4) {
#pragma unroll
    for (int m = 0; m < 2; ++m)
#pragma unroll
      for (int n = 0; n < 2; ++n)
#pragma unroll
        for (int r = 0; r < 4; ++r) {
          int row = (m << 4) + (lhi << 2) + r;
          int col = (wid << 5) + (n << 4) + l15;
          zcf[row * 132 + col] = acc[m][n][r] + bc[col];
        }
  } else {
#pragma unroll
    for (int m = 0; m < 2; ++m)
#pragma unroll
      for (int n = 0; n < 2; ++n)
#pragma unroll
        for (int r = 0; r < 4; ++r) {
          int row = (m << 4) + (lhi << 2) + r;
          int col = ((wid - 4) << 5) + (n << 4) + l15;
          zff[row * 132 + col] = acc[m][n][r] + bfv[col];
        }
  }
#pragma unroll
  for (int i = 0; i < 2; ++i) {
    int idx = t + i * 512;
    int row = idx >> 4, p = idx & 15;
    const float4 u0 = *(const float4*)&ccb[(row << 7) + (p << 3)];
    const float4 u1 = *(const float4*)&ccb[(row << 7) + (p << 3) + 4];
    *(uint4*)&cbb[row * 136 + (p << 3)] = pack8(u0, u1);
    float s2 = u0.x*u0.x + u0.y*u0.y + u0.z*u0.z + u0.w*u0.w
             + u1.x*u1.x + u1.y*u1.y + u1.z*u1.z + u1.w*u1.w;
    s2 += __shfl_xor(s2, 1); s2 += __shfl_xor(s2, 2);
    s2 += __shfl_xor(s2, 4); s2 += __shfl_xor(s2, 8);
    if (p == 0) cnS[row] = s2;
  }
  __syncthreads();

  // E2: LayerNorm(z_c); ||z||^2; z -> bf16
  {
    const int r = t >> 4, p = t & 15;
    float v[8];
    const float4 u0 = *(const float4*)&zcf[r * 132 + (p << 3)];
    const float4 u1 = *(const float4*)&zcf[r * 132 + (p << 3) + 4];
    v[0]=u0.x; v[1]=u0.y; v[2]=u0.z; v[3]=u0.w; v[4]=u1.x; v[5]=u1.y; v[6]=u1.z; v[7]=u1.w;
    float s = 0.f, s2 = 0.f;
#pragma unroll
    for (int j = 0; j < 8; ++j) { s += v[j]; s2 += v[j] * v[j]; }
#pragma unroll
    for (int off = 1; off < 16; off <<= 1) { s += __shfl_xor(s, off); s2 += __shfl_xor(s2, off); }
    const float mu   = s * (1.f / 128.f);
    const float rstd = rsqrtf(s2 * (1.f / 128.f) - mu * mu + 1e-5f);
    float s2n = 0.f;
#pragma unroll
    for (int j = 0; j < 8; ++j) {
      int col = (p << 3) + j;
      float vv = (v[j] - mu) * rstd * gc[col] + betac[col];
      v[j] = vv; s2n += vv * vv;
    }
#pragma unroll
    for (int off = 1; off < 16; off <<= 1) s2n += __shfl_xor(s2n, off);
    if (p == 0) zn[r] = s2n;
    *(uint4*)&zbb[r * 136 + (p << 3)] =
        make_uint4(pack2(v[0], v[1]), pack2(v[2], v[3]), pack2(v[4], v[5]), pack2(v[6], v[7]));
  }
  __syncthreads();

  // E3: coarse distances via MFMA
  {
    const int cg = wid & 3, zg = wid >> 2;
    f32x4 dacc = (f32x4){0.f, 0.f, 0.f, 0.f};
#pragma unroll
    for (int ks = 0; ks < 4; ++ks) {
      const int lk = (ks << 5) + (lhi << 3);
      bf16x8 a = *(const bf16x8*)&cbb[((cg << 4) + l15) * 136 + lk];
      bf16x8 b = *(const bf16x8*)&zbb[((zg << 4) + l15) * 136 + lk];
      dacc = __builtin_amdgcn_mfma_f32_16x16x32_bf16(a, b, dacc, 0, 0, 0);
    }
    float bd = 3.4e38f; int bi = 0;
#pragma unroll
    for (int r = 0; r < 4; ++r) {
      int code = (cg << 4) + (lhi << 2) + r;
      float d = cnS[code] - 2.f * dacc[r];
      if (d < bd || (d == bd && code < bi)) { bd = d; bi = code; }
    }
#pragma unroll
    for (int off = 16; off < 64; off <<= 1) {
      float od = __shfl_xor(bd, off); int oi = __shfl_xor(bi, off);
      if (od < bd || (od == bd && oi < bi)) { bd = od; bi = oi; }
    }
    if (lhi == 0) { dmS[cg * 32 + (zg << 4) + l15] = bd; imS[cg * 32 + (zg << 4) + l15] = bi; }
  }
  __syncthreads();

  // E4: final coarse argmin + loss partial + ci
  if (t < 32) {
    float bd = dmS[t]; int bi = imS[t];
#pragma unroll
    for (int w = 1; w < 4; ++w) {
      float od = dmS[w * 32 + t]; int oi = imS[w * 32 + t];
      if (od < bd || (od == bd && oi < bi)) { bd = od; bi = oi; }
    }
    ci_g[m0 + t] = bi;
    cxS[t] = bi;
    float lp = bd + zn[t];
#pragma unroll
    for (int off = 1; off < 32; off <<= 1) lp += __shfl_xor(lp, off);
    if (t == 0) coarse_partial[bid] = lp;
  }
  __syncthreads();

  // E5: stage Wfz (from Wf f32) + zqb (from ccb f32); write out0
  {
#pragma unroll
    for (int i = 0; i < 4; ++i) {
      int idx = t + i * 512;
      int row = idx >> 4, p = idx & 15;
      const float4 w0 = *(const float4*)&Wf[(size_t)row * HFD + 1024 + (p << 3)];
      const float4 w1 = *(const float4*)&Wf[(size_t)row * HFD + 1024 + (p << 3) + 4];
      *(uint4*)&Wz[row * 136 + (p << 3)] = pack8(w0, w1);
    }
    const int r = t >> 4, p = t & 15;
    const int c = cxS[r];
    const float4 q0 = *(const float4*)&ccb[(c << 7) + (p << 3)];
    const float4 q1 = *(const float4*)&ccb[(c << 7) + (p << 3) + 4];
    *(uint4*)&zqb[r * 136 + (p << 3)] = pack8(q0, q1);
    *(float4*)&out0[(size_t)(m0 + r) * DD + (p << 3)]     = q0;
    *(float4*)&out0[(size_t)(m0 + r) * DD + (p << 3) + 4] = q1;
  }
  __syncthreads();

  // E6: zff += zcq @ Wfz^T
  {
    f32x4 a2[2];
    a2[0] = (f32x4){0.f, 0.f, 0.f, 0.f};
    a2[1] = (f32x4){0.f, 0.f, 0.f, 0.f};
#pragma unroll
    for (int ks = 0; ks < 4; ++ks) {
      const int lk = (ks << 5) + (lhi << 3);
      bf16x8 a0 = *(const bf16x8*)&zqb[l15 * 136 + lk];
      bf16x8 a1 = *(const bf16x8*)&zqb[(16 + l15) * 136 + lk];
      bf16x8 b  = *(const bf16x8*)&Wz[((wid << 4) + l15) * 136 + lk];
      a2[0] = __builtin_amdgcn_mfma_f32_16x16x32_bf16(a0, b, a2[0], 0, 0, 0);
      a2[1] = __builtin_amdgcn_mfma_f32_16x16x32_bf16(a1, b, a2[1], 0, 0, 0);
    }
#pragma unroll
    for (int m = 0; m < 2; ++m)
#pragma unroll
      for (int r = 0; r < 4; ++r)
        zff[((m << 4) + (lhi << 2) + r) * 132 + (wid << 4) + l15] += a2[m][r];
  }
  __syncthreads();

  // E7: LayerNorm(z_f) -> zf_bf + zfn
  {
    const int r = t >> 4, p = t & 15;
    float v[8];
    const float4 u0 = *(const float4*)&zff[r * 132 + (p << 3)];
    const float4 u1 = *(const float4*)&zff[r * 132 + (p << 3) + 4];
    v[0]=u0.x; v[1]=u0.y; v[2]=u0.z; v[3]=u0.w; v[4]=u1.x; v[5]=u1.y; v[6]=u1.z; v[7]=u1.w;
    float s = 0.f, s2 = 0.f;
#pragma unroll
    for (int j = 0; j < 8; ++j) { s += v[j]; s2 += v[j] * v[j]; }
#pragma unroll
    for (int off = 1; off < 16; off <<= 1) { s += __shfl_xor(s, off); s2 += __shfl_xor(s2, off); }
    const float mu   = s * (1.f / 128.f);
    const float rstd = rsqrtf(s2 * (1.f / 128.f) - mu * mu + 1e-5f);
    float s2n = 0.f;
    unsigned int o[4];
#pragma unroll
    for (int jj = 0; jj < 4; ++jj) {
      int col = (p << 3) + 2 * jj;
      float v0 = (v[2 * jj]     - mu) * rstd * gf[col]     + betaf[col];
      float v1 = (v[2 * jj + 1] - mu) * rstd * gf[col + 1] + betaf[col + 1];
      s2n += v0 * v0 + v1 * v1;
      o[jj] = pack2(v0, v1);
    }
#pragma unroll
    for (int off = 1; off < 16; off <<= 1) s2n += __shfl_xor(s2n, off);
    if (p == 0) zfn[m0 + r] = s2n;
    *(uint4*)&zf_bf[(size_t)(m0 + r) * DD + (p << 3)] = make_uint4(o[0], o[1], o[2], o[3]);
  }
}

// ---- K3F: fine VQ (self-staging f32 codebook + norms) + fused final -------
__global__ __launch_bounds__(256) void k3f(
    const unsigned short* __restrict__ zf_bf, const float* __restrict__ fcb,
    const float* __restrict__ zfn, const int* __restrict__ ci_g,
    float* __restrict__ out1, float* __restrict__ coarse_partial,
    float* __restrict__ fine_partial, float* __restrict__ outL,
    unsigned int* __restrict__ donecnt)
{
  extern __shared__ char smem[];
  unsigned short* Vb  = (unsigned short*)smem;            // [256][136]
  unsigned short* zfL = (unsigned short*)(smem + 69632);  // [32][136]
  int*   list = (int*)  (smem + 78336);                   // [2048]
  int*   ridS = (int*)  (smem + 86528);                   // [32]
  float* dmS  = (float*)(smem + 86656);                   // [4][32]
  int*   imS  = (int*)  (smem + 87168);                   // [4][32]
  int*   fiS  = (int*)  (smem + 87680);                   // [32]
  int*   wsum = (int*)  (smem + 87808);                   // [8]
  float* cnormS = (float*)(smem + 87840);                 // [256]
  int*   lastF  = (int*)(smem + 88864);                   // [1]

  const int g = blockIdx.y, cx = blockIdx.x;   // cx in [0,4)
  const int t = threadIdx.x, lane = t & 63, wid = t >> 6;
  const int l15 = lane & 15, lhi = lane >> 4;

  // stage group codebook (f32 -> bf16) + per-row norms (f32, shfl-reduced)
#pragma unroll
  for (int i = 0; i < 16; ++i) {
    int idx = t + i * 256;
    int row = idx >> 4, p = idx & 15;
    const float* src = &fcb[((size_t)g * NK1 + row) * DD + (p << 3)];
    const float4 u0 = *(const float4*)src;
    const float4 u1 = *(const float4*)(src + 4);
    *(uint4*)&Vb[row * 136 + (p << 3)] = pack8(u0, u1);
    float s2 = u0.x*u0.x + u0.y*u0.y + u0.z*u0.z + u0.w*u0.w
             + u1.x*u1.x + u1.y*u1.y + u1.z*u1.z + u1.w*u1.w;
    s2 += __shfl_xor(s2, 1); s2 += __shfl_xor(s2, 2);
    s2 += __shfl_xor(s2, 4); s2 += __shfl_xor(s2, 8);
    if (p == 0) cnormS[row] = s2;
  }

  // deterministic compaction of {i : ci_g[i]==g}
  const int seg = t * 32;
  int mcount = 0;
#pragma unroll 8
  for (int q = 0; q < 32; ++q) mcount += (ci_g[seg + q] == g);
  int v = mcount;
#pragma unroll
  for (int off = 1; off < 64; off <<= 1) {
    int o = __shfl_up(v, off);
    if (lane >= off) v += o;
  }
  if (lane == 63) wsum[wid] = v;
  __syncthreads();

  float cnr[4];
#pragma unroll
  for (int n = 0; n < 4; ++n) cnr[n] = cnormS[wid * 64 + n * 16 + l15];

  if (t == 0) {
    int run = 0;
#pragma unroll
    for (int w = 0; w < 4; ++w) { int c = wsum[w]; wsum[w] = run; run += c; }
    wsum[4] = run;
  }
  __syncthreads();
  const int total = wsum[4];
  const int tcap = total > 2048 ? 2048 : total;
  {
    int j = wsum[wid] + v - mcount;
    for (int q = 0; q < 32; ++q) {
      if (ci_g[seg + q] == g) { if (j < 2048) list[j] = seg + q; ++j; }
    }
  }
  __syncthreads();

  float lp = 0.f;
  for (int r0 = cx * 32; r0 < tcap; r0 += 128) {
    __syncthreads();
    if (t < 32) ridS[t] = (r0 + t < tcap) ? list[r0 + t] : -1;
    __syncthreads();
#pragma unroll
    for (int i = 0; i < 2; ++i) {
      int idx = t + i * 256; int row = idx >> 4, c8 = (idx & 15) * 8;
      int rid = ridS[row];
      uint4 vv = make_uint4(0u, 0u, 0u, 0u);
      if (rid >= 0) vv = *(const uint4*)&zf_bf[(size_t)rid * DD + c8];
      *(uint4*)&zfL[row * 136 + c8] = vv;
    }
    __syncthreads();
    f32x4 acc[2][4];
#pragma unroll
    for (int m = 0; m < 2; ++m)
#pragma unroll
      for (int n = 0; n < 4; ++n) acc[m][n] = (f32x4){0.f, 0.f, 0.f, 0.f};
#pragma unroll
    for (int ks = 0; ks < 4; ++ks) {
      const int lk = ks * 32 + lhi * 8;
      bf16x8 a0 = *(const bf16x8*)&zfL[l15 * 136 + lk];
      bf16x8 a1 = *(const bf16x8*)&zfL[(16 + l15) * 136 + lk];
#pragma unroll
      for (int n = 0; n < 4; ++n) {
        bf16x8 b = *(const bf16x8*)&Vb[(wid * 64 + n * 16 + l15) * 136 + lk];
        acc[0][n] = __builtin_amdgcn_mfma_f32_16x16x32_bf16(a0, b, acc[0][n], 0, 0, 0);
        acc[1][n] = __builtin_amdgcn_mfma_f32_16x16x32_bf16(a1, b, acc[1][n], 0, 0, 0);
      }
    }
#pragma unroll
    for (int m = 0; m < 2; ++m)
#pragma unroll
      for (int r = 0; r < 4; ++r) {
        float bd = 3.4e38f; int bi = 0;
#pragma unroll
        for (int n = 0; n < 4; ++n) {
          int code = wid * 64 + n * 16 + l15;
          float d = cnr[n] - 2.f * acc[m][n][r];
          if (d < bd || (d == bd && code < bi)) { bd = d; bi = code; }
        }
#pragma unroll
        for (int off = 1; off < 16; off <<= 1) {
          float od = __shfl_xor(bd, off); int oi = __shfl_xor(bi, off);
          if (od < bd || (od == bd && oi < bi)) { bd = od; bi = oi; }
        }
        if (l15 == 0) {
          int row = m * 16 + lhi * 4 + r;
          dmS[wid * 32 + row] = bd; imS[wid * 32 + row] = bi;
        }
      }
    __syncthreads();
    if (t < 32) {
      float bd = dmS[t]; int bi = imS[t];
#pragma unroll
      for (int w = 1; w < 4; ++w) {
        float od = dmS[w * 32 + t]; int oi = imS[w * 32 + t];
        if (od < bd || (od == bd && oi < bi)) { bd = od; bi = oi; }
      }
      fiS[t] = bi;
      int rid = ridS[t];
      if (rid >= 0) lp += bd + zfn[rid];
    }
    __syncthreads();
    {
      const int r = t >> 3, p = t & 7;
      const int rid = ridS[r];
      if (rid >= 0) {
        const int fi = fiS[r];
        const float* qr = &fcb[((size_t)g * NK1 + fi) * DD + p * 16];
        float* orow = &out1[(size_t)rid * DD + p * 16];
#pragma unroll
        for (int q = 0; q < 4; ++q) *(float4*)&orow[q * 4] = *(const float4*)&qr[q * 4];
      }
    }
  }
#pragma unroll
  for (int off = 1; off < 32; off <<= 1) lp += __shfl_xor(lp, off);
  if (t == 0) fine_partial[g * 4 + cx] = lp;

  // ---- fused final reduce: last finished block sums all partials ----
  __syncthreads();
  if (t == 0) {
    __threadfence();
    unsigned int old = __hip_atomic_fetch_add(donecnt, 1u, __ATOMIC_ACQ_REL,
                                              __HIP_MEMORY_SCOPE_AGENT);
    lastF[0] = (old == 255u) ? 1 : 0;
  }
  __syncthreads();
  if (lastF[0] && t < 64) {
    float s = 0.f;
#pragma unroll
    for (int i = 0; i < 4; ++i) {
      s += __hip_atomic_load(&coarse_partial[t + i * 64], __ATOMIC_RELAXED,
                             __HIP_MEMORY_SCOPE_AGENT);
      s += __hip_atomic_load(&fine_partial[t + i * 64], __ATOMIC_RELAXED,
                             __HIP_MEMORY_SCOPE_AGENT);
    }
#pragma unroll
    for (int off = 1; off < 64; off <<= 1) s += __shfl_xor(s, off);
    if (t == 0) outL[0] = 1.25f * s / 1048576.0f;
  }
}

// ---- launcher: 2 kernel nodes, no memsets ---------------------------------
extern "C" void kernel_launch(void* const* d_in, const int* in_sizes, int n_in,
                              void* d_out, int out_size, void* d_ws, size_t ws_size,
                              hipStream_t stream) {
  const float* x     = (const float*)d_in[0];
  const float* Wc    = (const float*)d_in[1];
  const float* bc    = (const float*)d_in[2];
  const float* gc    = (const float*)d_in[3];
  const float* betac = (const float*)d_in[4];
  const float* ccb   = (const float*)d_in[5];
  const float* Wf    = (const float*)d_in[6];
  const float* bfv   = (const float*)d_in[7];
  const float* gf    = (const float*)d_in[8];
  const float* betaf = (const float*)d_in[9];
  const float* fcb   = (const float*)d_in[10];

  float* out0 = (float*)d_out;
  float* out1 = out0 + (size_t)NB * DD;
  float* outL = out0 + (size_t)2 * NB * DD;

  char* ws = (char*)d_ws;
  unsigned short* zf_bf  = (unsigned short*)(ws);
  float*          zfn    = (float*)(ws + 2097152);
  int*            ci_g   = (int*)(ws + 2129920);
  float* coarse_partial  = (float*)(ws + 2162688);
  float* fine_partial    = (float*)(ws + 2163712);
  unsigned int*   donecnt = (unsigned int*)(ws + 2164736);

  hipFuncSetAttribute(reinterpret_cast<const void*>(kG2),
                      hipFuncAttributeMaxDynamicSharedMemorySize, 88448);
  hipFuncSetAttribute(reinterpret_cast<const void*>(k3f),
                      hipFuncAttributeMaxDynamicSharedMemorySize, 88896);

  hipLaunchKernelGGL(kG2, dim3(256), dim3(512), 88448, stream,
                     x, Wc, Wf, ccb, bc, gc, betac, bfv, gf, betaf,
                     out0, zf_bf, zfn, ci_g, coarse_partial, donecnt);
  hipLaunchKernelGGL(k3f, dim3(4, 64), dim3(256), 88896, stream,
                     zf_bf, fcb, zfn, ci_g, out1, coarse_partial, fine_partial,
                     outL, donecnt);
}